// Round 18
// baseline (129.226 us; speedup 1.0000x reference)
//
#include <hip/hip_runtime.h>
#include <hip/hip_fp16.h>
#include <math.h>

#define IN_FEATS 64
#define N_NODES 100000
#define N_EDGES 1600000
#define BSHIFT 7
#define NPB 128                              // nodes per bucket
#define NBUCK ((N_NODES + NPB - 1) / NPB)    // 782
#define CAP 4088                             // padded bucket capacity (mean 2046, sigma 45)
#define PCHUNK 16384
#define PGRID ((N_EDGES + PCHUNK - 1) / PCHUNK)  // 98
#define NGRP (N_NODES / 16)                  // 6250 (exact)

// sqrt(64 * log2(e)) : exp(-64 t^2) == exp2(-((K t))^2)
#define KSCALE 9.6089785f

typedef __attribute__((ext_vector_type(8))) short short8_t;
typedef __attribute__((ext_vector_type(4))) float f32x4_t;

#define MFMA16(a, b, c) __builtin_amdgcn_mfma_f32_16x16x32_bf16(a, b, c, 0, 0, 0)

__device__ __forceinline__ unsigned short bf16_rne(float x) {
    unsigned u = __float_as_uint(x);
    unsigned r = u + 0x7FFFu + ((u >> 16) & 1u);
    return (unsigned short)(r >> 16);
}

__device__ __forceinline__ short8_t u4_to_s8(uint4 v) {
    union { uint4 u; short8_t s; } cv; cv.u = v; return cv.s;
}

// split 8 f32 (two float4) into hi/lo bf16 fragments
__device__ __forceinline__ void split8(float4 a, float4 b,
                                       short8_t* hi, short8_t* lo) {
    short8_t h, l;
#define SP(I, X) { unsigned short hu = bf16_rne(X); \
        float hf = __uint_as_float((unsigned)hu << 16); \
        unsigned short lu = bf16_rne((X) - hf); \
        h[I] = (short)hu; l[I] = (short)lu; }
    SP(0, a.x) SP(1, a.y) SP(2, a.z) SP(3, a.w)
    SP(4, b.x) SP(5, b.y) SP(6, b.z) SP(7, b.w)
#undef SP
    *hi = h; *lo = l;
}

// ---------------------------------------------------------------------------
// full edge coefficient (fallback path only)
// ---------------------------------------------------------------------------
__device__ __forceinline__ float edge_coef(float d, float mu) {
    float t = d - mu;
    float rbf = __expf(-64.0f * t * t);
    float x  = (d - 0.8f) * 5.0f;
    float xc = fminf(fmaxf(x, 0.0f), 1.0f);
    float ramp = 0.5f * (__cosf(3.14159265358979323846f * xc) + 1.0f);
    float fc = (d <= 0.8f) ? 1.0f : ((d >= 1.0f) ? 0.0f : ramp);
    return rbf * fc;
}

__device__ __forceinline__ float cutoff_fc(float d) {
    float x  = (d - 0.8f) * 5.0f;
    float xc = fminf(fmaxf(x, 0.0f), 1.0f);
    float ramp = 0.5f * (__cosf(3.14159265358979323846f * xc) + 1.0f);
    return (d <= 0.8f) ? 1.0f : ((d >= 1.0f) ? 0.0f : ramp);
}

// ---------------------------------------------------------------------------
// Init: bcursor, sentinel, and W1/W2 -> MFMA fragment tables (hi/lo bf16).
// ---------------------------------------------------------------------------
__global__ __launch_bounds__(256) void init_kernel(int* __restrict__ bcursor,
                                                   int* __restrict__ offs,
                                                   const float* __restrict__ W1,
                                                   const float* __restrict__ W2,
                                                   uint4* __restrict__ wfrag) {
    int i = blockIdx.x * 256 + threadIdx.x;
    if (i < NBUCK) bcursor[i] = i * CAP;
    if (i == 0) offs[N_NODES] = N_EDGES;
    if (i < 2048) {
        int lane  = i & 63;
        int tile  = (i >> 6) & 7;     // t*4+n
        int hl    = (i >> 9) & 1;
        int layer = (i >> 10) & 1;
        const float* W = layer ? W2 : W1;
        int kbase = (tile >> 2) * 32 + (lane >> 4) * 8;
        int j     = (tile & 3) * 16 + (lane & 15);
        unsigned p[4];
        #pragma unroll
        for (int e = 0; e < 8; e += 2) {
            float x0 = W[(kbase + e) * 64 + j];
            float x1 = W[(kbase + e + 1) * 64 + j];
            unsigned short u0, u1;
            if (hl == 0) {
                u0 = bf16_rne(x0);
                u1 = bf16_rne(x1);
            } else {
                unsigned short h0 = bf16_rne(x0);
                unsigned short h1 = bf16_rne(x1);
                u0 = bf16_rne(x0 - __uint_as_float((unsigned)h0 << 16));
                u1 = bf16_rne(x1 - __uint_as_float((unsigned)h1 << 16));
            }
            p[e >> 1] = (unsigned)u0 | ((unsigned)u1 << 16);
        }
        wfrag[i] = make_uint4(p[0], p[1], p[2], p[3]);
    }
}

// ---------------------------------------------------------------------------
// h -> bf16 conversion (halves agg gather bytes). 8 elems/thread.
// ---------------------------------------------------------------------------
__global__ __launch_bounds__(256) void h2bf16_kernel(const float* __restrict__ h,
                                                     unsigned short* __restrict__ hb) {
    int i = blockIdx.x * 256 + threadIdx.x;    // one per 8 elems
    if (i < N_NODES * 8) {
        const float4* p = (const float4*)(h + (size_t)i * 8);
        float4 a = p[0], b = p[1];
        unsigned u0 = (unsigned)bf16_rne(a.x) | ((unsigned)bf16_rne(a.y) << 16);
        unsigned u1 = (unsigned)bf16_rne(a.z) | ((unsigned)bf16_rne(a.w) << 16);
        unsigned u2 = (unsigned)bf16_rne(b.x) | ((unsigned)bf16_rne(b.y) << 16);
        unsigned u3 = (unsigned)bf16_rne(b.z) | ((unsigned)bf16_rne(b.w) << 16);
        *(uint4*)(hb + (size_t)i * 8) = make_uint4(u0, u1, u2, u3);
    }
}

// ---------------------------------------------------------------------------
// Partition into padded bucket staging (d_out). Block-chunked reservation.
// Record: {src | (dst_local<<17),  (log2fc_f16 << 16) | d_unorm16}
// ---------------------------------------------------------------------------
__global__ __launch_bounds__(1024) void partition_kernel(const int* __restrict__ dst,
                                                         const int* __restrict__ src,
                                                         const float* __restrict__ dist,
                                                         int* __restrict__ bcursor,
                                                         int2* __restrict__ brec) {
    __shared__ int hist[NBUCK];
    __shared__ int base_[NBUCK];
    int tid = threadIdx.x;
    for (int i = tid; i < NBUCK; i += 1024) hist[i] = 0;
    __syncthreads();

    int e0 = blockIdx.x * PCHUNK;
    int e1 = min(e0 + PCHUNK, N_EDGES);

    for (int t = e0 + tid; t < e1; t += 1024)
        atomicAdd(&hist[dst[t] >> BSHIFT], 1);
    __syncthreads();

    for (int i = tid; i < NBUCK; i += 1024) {
        int hv = hist[i];
        if (hv) base_[i] = atomicAdd(&bcursor[i], hv);
        hist[i] = 0;      // reuse as local cursor
    }
    __syncthreads();

    for (int t = e0 + tid; t < e1; t += 1024) {
        int d  = dst[t];
        int b  = d >> BSHIFT;
        int r  = atomicAdd(&hist[b], 1);
        float dv = dist[t];
        float fc = cutoff_fc(dv);
        float lfc = (fc > 0.0f) ? __log2f(fc) : -512.0f;
        unsigned dq = (unsigned)(fminf(fmaxf(dv, 0.0f), 1.0f) * 65535.0f + 0.5f);
        unsigned hf = (unsigned)__half_as_ushort(__float2half(lfc));
        int2 rec;
        rec.x = src[t] | ((d & (NPB - 1)) << 17);
        rec.y = (int)((hf << 16) | dq);
        brec[(size_t)base_[b] + r] = rec;
    }
}

// ---------------------------------------------------------------------------
// Compact scan: cnt[b] = bcursor[b]-b*CAP; boffs = exclusive scan.
// ---------------------------------------------------------------------------
__global__ __launch_bounds__(1024) void bscan_kernel(const int* __restrict__ bcursor,
                                                     int* __restrict__ boffs) {
    __shared__ int lds[1024];
    int tid = threadIdx.x;
    int v = (tid < NBUCK) ? (bcursor[tid] - tid * CAP) : 0;
    lds[tid] = v;
    __syncthreads();
    for (int off = 1; off < 1024; off <<= 1) {
        int x = (tid >= off) ? lds[tid - off] : 0;
        __syncthreads();
        lds[tid] += x;
        __syncthreads();
    }
    if (tid < NBUCK) boffs[tid] = lds[tid] - v;
    if (tid == 0) boffs[NBUCK] = N_EDGES;
}

// ---------------------------------------------------------------------------
// Node-sort v2: single global read. Stage bucket records in LDS, count,
// scan, scatter from LDS -> compact per-node CSR (rec_sorted, offs).
// ---------------------------------------------------------------------------
__global__ __launch_bounds__(256) void node_sort_kernel(const int2* __restrict__ brec,
                                                        const int* __restrict__ boffs,
                                                        int2* __restrict__ rec_sorted,
                                                        int* __restrict__ offs) {
    __shared__ int cntL[NPB];
    __shared__ int scanL[NPB];
    __shared__ int curL[NPB];
    __shared__ int2 stage[CAP];

    int b   = blockIdx.x;
    int tid = threadIdx.x;
    int beg = boffs[b];
    int cnt = boffs[b + 1] - beg;
    size_t pbase = (size_t)b * CAP;
    int node0 = b << BSHIFT;

    for (int i = tid; i < NPB; i += 256) cntL[i] = 0;
    __syncthreads();

    for (int t = tid; t < cnt; t += 256) {
        int2 r = brec[pbase + t];
        stage[t] = r;
        atomicAdd(&cntL[(r.x >> 17) & (NPB - 1)], 1);
    }
    __syncthreads();

    if (tid < NPB) scanL[tid] = cntL[tid];
    __syncthreads();
    for (int off = 1; off < NPB; off <<= 1) {
        int x = 0;
        if (tid < NPB && tid >= off) x = scanL[tid - off];
        __syncthreads();
        if (tid < NPB) scanL[tid] += x;
        __syncthreads();
    }
    if (tid < NPB) {
        int excl = scanL[tid] - cntL[tid];
        curL[tid] = excl;
        int node = node0 + tid;
        if (node < N_NODES) offs[node] = beg + excl;
    }
    __syncthreads();

    for (int t = tid; t < cnt; t += 256) {
        int2 r = stage[t];
        int dl = (r.x >> 17) & (NPB - 1);
        int p  = atomicAdd(&curL[dl], 1);
        rec_sorted[(size_t)beg + p] = r;
    }
}

// ---------------------------------------------------------------------------
// Aggregation (bf16 h): one wave per node, lane k owns feature k.
// 128B/record wave gather; coef = exp2(lfc - t^2).
// ---------------------------------------------------------------------------
__global__ __launch_bounds__(256) void agg_bf16_kernel(
    const unsigned short* __restrict__ hb,
    const int* __restrict__ offs,
    const int2* __restrict__ rec_sorted,
    float* __restrict__ out)
{
    int w    = threadIdx.x >> 6;
    int lane = threadIdx.x & 63;
    int node = blockIdx.x * 4 + w;
    if (node >= N_NODES) return;

    int beg = __builtin_amdgcn_readfirstlane(offs[node]);
    int end = __builtin_amdgcn_readfirstlane(offs[node + 1]);
    float muK = (float)lane * (KSCALE / 63.0f);
    float acc0 = 0.0f, acc1 = 0.0f;

#define REC(J, ACC) { \
        int2 r_ = rec_sorted[(size_t)(J)]; \
        int rx_ = __builtin_amdgcn_readfirstlane(r_.x); \
        unsigned ry_ = (unsigned)__builtin_amdgcn_readfirstlane(r_.y); \
        unsigned hvu_ = (unsigned)hb[((size_t)(rx_ & 0x1FFFF) << 6) + lane]; \
        float hv_ = __uint_as_float(hvu_ << 16); \
        float dqf_ = (float)(ry_ & 0xFFFFu); \
        float lfc_ = __half2float(__ushort_as_half((unsigned short)(ry_ >> 16))); \
        float t_  = fmaf(dqf_, (KSCALE / 65535.0f), -muK); \
        float a_  = fmaf(-t_, t_, lfc_); \
        ACC = fmaf(hv_, exp2f(a_), ACC); }

    int i = beg;
    int main_end = beg + ((end - beg) & ~7);
    for (; i < main_end; i += 8) {
        REC(i + 0, acc0) REC(i + 1, acc1) REC(i + 2, acc0) REC(i + 3, acc1)
        REC(i + 4, acc0) REC(i + 5, acc1) REC(i + 6, acc0) REC(i + 7, acc1)
    }
    for (; i < end; ++i) { REC(i, acc0) }
#undef REC

    out[(size_t)node * 64 + lane] = acc0 + acc1;
}

// ---------------------------------------------------------------------------
// Aggregation (f32 h) — used when ws too small for the bf16 copy.
// ---------------------------------------------------------------------------
__global__ __launch_bounds__(256) void agg_kernel(
    const float* __restrict__ h,
    const int* __restrict__ offs,
    const int2* __restrict__ rec_sorted,
    float* __restrict__ out)
{
    int w    = threadIdx.x >> 6;
    int lane = threadIdx.x & 63;
    int node = blockIdx.x * 4 + w;
    if (node >= N_NODES) return;

    int beg = __builtin_amdgcn_readfirstlane(offs[node]);
    int end = __builtin_amdgcn_readfirstlane(offs[node + 1]);
    float muK = (float)lane * (KSCALE / 63.0f);
    float acc0 = 0.0f, acc1 = 0.0f;

#define REC(J, ACC) { \
        int2 r_ = rec_sorted[(size_t)(J)]; \
        int rx_ = __builtin_amdgcn_readfirstlane(r_.x); \
        unsigned ry_ = (unsigned)__builtin_amdgcn_readfirstlane(r_.y); \
        float hv_ = h[((size_t)(rx_ & 0x1FFFF) << 6) + lane]; \
        float dqf_ = (float)(ry_ & 0xFFFFu); \
        float lfc_ = __half2float(__ushort_as_half((unsigned short)(ry_ >> 16))); \
        float t_  = fmaf(dqf_, (KSCALE / 65535.0f), -muK); \
        float a_  = fmaf(-t_, t_, lfc_); \
        ACC = fmaf(hv_, exp2f(a_), ACC); }

    int i = beg;
    int main_end = beg + ((end - beg) & ~7);
    for (; i < main_end; i += 8) {
        REC(i + 0, acc0) REC(i + 1, acc1) REC(i + 2, acc0) REC(i + 3, acc1)
        REC(i + 4, acc0) REC(i + 5, acc1) REC(i + 6, acc0) REC(i + 7, acc1)
    }
    for (; i < end; ++i) { REC(i, acc0) }
#undef REC

    out[(size_t)node * 64 + lane] = acc0 + acc1;
}

// ---------------------------------------------------------------------------
// MLP v6 — MFMA. Per wave: 16 nodes. Split-bf16 3-pass.
// ---------------------------------------------------------------------------
__global__ __launch_bounds__(256) void mlp_kernel(
    float* __restrict__ io, const uint4* __restrict__ wfrag,
    const float* __restrict__ b1, const float* __restrict__ b2)
{
    __shared__ float hidL[4][16][68];

    int tid  = threadIdx.x;
    int lane = tid & 63;
    int wv   = tid >> 6;
    int grp  = blockIdx.x * 4 + wv;
    if (grp >= NGRP) return;
    int node0 = grp * 16;
    int lrow = lane & 15, lk = lane >> 4;

    const float* arow = io + (size_t)(node0 + lrow) * 64 + lk * 8;
    float4 t0 = *(const float4*)(arow);
    float4 t1 = *(const float4*)(arow + 4);
    float4 t2 = *(const float4*)(arow + 32);
    float4 t3 = *(const float4*)(arow + 36);
    short8_t Ah0, Al0, Ah1, Al1;
    split8(t0, t1, &Ah0, &Al0);
    split8(t2, t3, &Ah1, &Al1);

    f32x4_t acc[4];
    #pragma unroll
    for (int n = 0; n < 4; ++n) {
        float b = b1[n * 16 + lrow];
        acc[n] = (f32x4_t){b, b, b, b};
    }
    #pragma unroll
    for (int n = 0; n < 4; ++n) {
        short8_t wh0 = u4_to_s8(wfrag[(n) * 64 + lane]);
        short8_t wh1 = u4_to_s8(wfrag[(4 + n) * 64 + lane]);
        short8_t wl0 = u4_to_s8(wfrag[512 + n * 64 + lane]);
        short8_t wl1 = u4_to_s8(wfrag[512 + (4 + n) * 64 + lane]);
        f32x4_t c = acc[n];
        c = MFMA16(Ah0, wh0, c);
        c = MFMA16(Ah1, wh1, c);
        c = MFMA16(Ah0, wl0, c);
        c = MFMA16(Ah1, wl1, c);
        c = MFMA16(Al0, wh0, c);
        c = MFMA16(Al1, wh1, c);
        acc[n] = c;
    }

    #pragma unroll
    for (int n = 0; n < 4; ++n) {
        #pragma unroll
        for (int r = 0; r < 4; ++r) {
            float v = acc[n][r];
            float e = exp2f(v * 1.44269504089f);
            float sp = 0.69314718056f * __log2f(1.0f + e);
            v = (v > 20.0f) ? v : sp;
            hidL[wv][lk * 4 + r][n * 16 + lrow] = v;
        }
    }
    __threadfence_block();

    const float* hrow = &hidL[wv][lrow][lk * 8];
    float4 h0 = *(const float4*)(hrow);
    float4 h1 = *(const float4*)(hrow + 4);
    float4 h2 = *(const float4*)(hrow + 32);
    float4 h3 = *(const float4*)(hrow + 36);
    short8_t Bh0, Bl0, Bh1, Bl1;
    split8(h0, h1, &Bh0, &Bl0);
    split8(h2, h3, &Bh1, &Bl1);

    f32x4_t oac[4];
    #pragma unroll
    for (int n = 0; n < 4; ++n) {
        float b = b2[n * 16 + lrow];
        oac[n] = (f32x4_t){b, b, b, b};
    }
    #pragma unroll
    for (int n = 0; n < 4; ++n) {
        short8_t wh0 = u4_to_s8(wfrag[1024 + n * 64 + lane]);
        short8_t wh1 = u4_to_s8(wfrag[1024 + (4 + n) * 64 + lane]);
        short8_t wl0 = u4_to_s8(wfrag[1536 + n * 64 + lane]);
        short8_t wl1 = u4_to_s8(wfrag[1536 + (4 + n) * 64 + lane]);
        f32x4_t c = oac[n];
        c = MFMA16(Bh0, wh0, c);
        c = MFMA16(Bh1, wh1, c);
        c = MFMA16(Bh0, wl0, c);
        c = MFMA16(Bh1, wl1, c);
        c = MFMA16(Bl0, wh0, c);
        c = MFMA16(Bl1, wh1, c);
        oac[n] = c;
    }

    #pragma unroll
    for (int n = 0; n < 4; ++n) {
        #pragma unroll
        for (int r = 0; r < 4; ++r) {
            io[(size_t)(node0 + lk * 4 + r) * 64 + n * 16 + lrow] = oac[n][r];
        }
    }
}

// ---------------------------------------------------------------------------
// Fallback (ws too small): atomic scatter-add path + simple MLP.
// ---------------------------------------------------------------------------
__global__ __launch_bounds__(256) void schnet_edge_kernel(
    const float* __restrict__ h,
    const float* __restrict__ dist,
    const int* __restrict__ src_idx,
    const int* __restrict__ dst_idx,
    float* __restrict__ agg)
{
    long long idx = (long long)blockIdx.x * 256 + threadIdx.x;
    int e = (int)(idx >> 6);
    if (e >= N_EDGES) return;
    int k = (int)(idx & 63);
    float d = dist[e];
    float c = edge_coef(d, (float)k * (1.0f / 63.0f));
    int s  = src_idx[e];
    int dn = dst_idx[e];
    atomicAdd(&agg[(long long)dn * 64 + k], h[(long long)s * 64 + k] * c);
}

__global__ __launch_bounds__(256) void mlp_fallback_kernel(
    float* __restrict__ io,
    const float* __restrict__ W1, const float* __restrict__ b1,
    const float* __restrict__ W2, const float* __restrict__ b2)
{
    __shared__ float sW1[64 * 64];
    __shared__ float sW2[64 * 64];
    __shared__ float sRow[4][64];
    __shared__ float sHid[4][64];
    int tid = threadIdx.x;
    for (int i = tid; i < 4096; i += 256) { sW1[i] = W1[i]; sW2[i] = W2[i]; }
    __syncthreads();
    int lane = tid & 63, w = tid >> 6;
    float bb1 = b1[lane], bb2 = b2[lane];
    for (int base = blockIdx.x * 4; base < N_NODES; base += gridDim.x * 4) {
        int node = base + w;
        if (node < N_NODES) sRow[w][lane] = io[(size_t)node * 64 + lane];
        __syncthreads();
        float a = bb1;
        #pragma unroll
        for (int k = 0; k < 64; ++k) a = fmaf(sRow[w][k], sW1[k * 64 + lane], a);
        sHid[w][lane] = (a > 20.f) ? a : log1pf(__expf(a));
        __syncthreads();
        float c = bb2;
        #pragma unroll
        for (int k = 0; k < 64; ++k) c = fmaf(sHid[w][k], sW2[k * 64 + lane], c);
        if (node < N_NODES) io[(size_t)node * 64 + lane] = c;
        __syncthreads();
    }
}

extern "C" void kernel_launch(void* const* d_in, const int* in_sizes, int n_in,
                              void* d_out, int out_size, void* d_ws, size_t ws_size,
                              hipStream_t stream) {
    const float* h    = (const float*)d_in[0];
    const float* dist = (const float*)d_in[1];
    const float* W1   = (const float*)d_in[2];
    const float* b1   = (const float*)d_in[3];
    const float* W2   = (const float*)d_in[4];
    const float* b2   = (const float*)d_in[5];
    const int* src    = (const int*)d_in[6];
    const int* dst    = (const int*)d_in[7];
    float* out        = (float*)d_out;

    // ws layout (bytes): wfrag 32KB | [hb 12.8MB bf16 path] | rec_sorted 12.8MB |
    //                    boffs[NBUCK+1] | bcursor[NBUCK] | offs[N+1]
    const size_t WFRAG_B = 32768;
    const size_t HB_B    = (size_t)N_NODES * 64 * 2;           // 12.8 MB
    const size_t RS_B    = (size_t)N_EDGES * 8;                // 12.8 MB
    const size_t INTS_B  = ((size_t)NBUCK + 1 + NBUCK + N_NODES + 1) * 4;
    size_t need_f32  = WFRAG_B + RS_B + INTS_B;
    size_t need_bf16 = WFRAG_B + HB_B + RS_B + INTS_B;

    if (ws_size >= need_f32) {
        bool use_bf16 = (ws_size >= need_bf16);
        char* p = (char*)d_ws;
        uint4* wfrag = (uint4*)p;              p += WFRAG_B;
        unsigned short* hb = (unsigned short*)p;
        if (use_bf16)                          p += HB_B;
        int2* rec_sorted = (int2*)p;           p += RS_B;
        int* boffs   = (int*)p;                // NBUCK+1
        int* bcursor = boffs + NBUCK + 1;
        int* offs    = bcursor + NBUCK;        // N+1

        // padded bucket staging in d_out (782*4088 recs = 25.57MB <= 25.6MB)
        int2* brec = (int2*)d_out;

        init_kernel<<<16, 256, 0, stream>>>(bcursor, offs, W1, W2, wfrag);
        if (use_bf16)
            h2bf16_kernel<<<(N_NODES * 8 + 255) / 256, 256, 0, stream>>>(h, hb);
        partition_kernel<<<PGRID, 1024, 0, stream>>>(dst, src, dist, bcursor, brec);
        bscan_kernel<<<1, 1024, 0, stream>>>(bcursor, boffs);
        node_sort_kernel<<<NBUCK, 256, 0, stream>>>(brec, boffs, rec_sorted, offs);
        if (use_bf16)
            agg_bf16_kernel<<<N_NODES / 4, 256, 0, stream>>>(hb, offs, rec_sorted, out);
        else
            agg_kernel<<<N_NODES / 4, 256, 0, stream>>>(h, offs, rec_sorted, out);
        mlp_kernel<<<(NGRP + 3) / 4, 256, 0, stream>>>(out, wfrag, b1, b2);
    } else {
        hipMemsetAsync(out, 0, (size_t)N_NODES * IN_FEATS * sizeof(float), stream);
        long long total = (long long)N_EDGES * 64;
        schnet_edge_kernel<<<(int)((total + 255) / 256), 256, 0, stream>>>(
            h, dist, src, dst, out);
        mlp_fallback_kernel<<<2048, 256, 0, stream>>>(out, W1, b1, W2, b2);
    }
}

// Round 19
// 126.960 us; speedup vs baseline: 1.0178x; 1.0178x over previous
//
#include <hip/hip_runtime.h>
#include <hip/hip_fp16.h>
#include <math.h>

#define IN_FEATS 64
#define N_NODES 100000
#define N_EDGES 1600000
#define BSHIFT 7
#define NPB 128                              // nodes per bucket
#define NBUCK ((N_NODES + NPB - 1) / NPB)    // 782
#define CAP 4088                             // padded bucket capacity (mean 2046, sigma 45)
#define PCHUNK 8192
#define PGRID ((N_EDGES + PCHUNK - 1) / PCHUNK)  // 196
#define NGRP (N_NODES / 16)                  // 6250 (exact)

// sqrt(64 * log2(e)) : exp(-64 t^2) == exp2(-((K t))^2)
#define KSCALE 9.6089785f

typedef __attribute__((ext_vector_type(8))) short short8_t;
typedef __attribute__((ext_vector_type(4))) float f32x4_t;

#define MFMA16(a, b, c) __builtin_amdgcn_mfma_f32_16x16x32_bf16(a, b, c, 0, 0, 0)

__device__ __forceinline__ unsigned short bf16_rne(float x) {
    unsigned u = __float_as_uint(x);
    unsigned r = u + 0x7FFFu + ((u >> 16) & 1u);
    return (unsigned short)(r >> 16);
}

__device__ __forceinline__ short8_t u4_to_s8(uint4 v) {
    union { uint4 u; short8_t s; } cv; cv.u = v; return cv.s;
}

// split 8 f32 (two float4) into hi/lo bf16 fragments
__device__ __forceinline__ void split8(float4 a, float4 b,
                                       short8_t* hi, short8_t* lo) {
    short8_t h, l;
#define SP(I, X) { unsigned short hu = bf16_rne(X); \
        float hf = __uint_as_float((unsigned)hu << 16); \
        unsigned short lu = bf16_rne((X) - hf); \
        h[I] = (short)hu; l[I] = (short)lu; }
    SP(0, a.x) SP(1, a.y) SP(2, a.z) SP(3, a.w)
    SP(4, b.x) SP(5, b.y) SP(6, b.z) SP(7, b.w)
#undef SP
    *hi = h; *lo = l;
}

// ---------------------------------------------------------------------------
// full edge coefficient (fallback path only)
// ---------------------------------------------------------------------------
__device__ __forceinline__ float edge_coef(float d, float mu) {
    float t = d - mu;
    float rbf = __expf(-64.0f * t * t);
    float x  = (d - 0.8f) * 5.0f;
    float xc = fminf(fmaxf(x, 0.0f), 1.0f);
    float ramp = 0.5f * (__cosf(3.14159265358979323846f * xc) + 1.0f);
    float fc = (d <= 0.8f) ? 1.0f : ((d >= 1.0f) ? 0.0f : ramp);
    return rbf * fc;
}

__device__ __forceinline__ float cutoff_fc(float d) {
    float x  = (d - 0.8f) * 5.0f;
    float xc = fminf(fmaxf(x, 0.0f), 1.0f);
    float ramp = 0.5f * (__cosf(3.14159265358979323846f * xc) + 1.0f);
    return (d <= 0.8f) ? 1.0f : ((d >= 1.0f) ? 0.0f : ramp);
}

// ---------------------------------------------------------------------------
// Init: bcursor, sentinel, and W1/W2 -> MFMA fragment tables (hi/lo bf16).
// ---------------------------------------------------------------------------
__global__ __launch_bounds__(256) void init_kernel(int* __restrict__ bcursor,
                                                   int* __restrict__ offs,
                                                   const float* __restrict__ W1,
                                                   const float* __restrict__ W2,
                                                   uint4* __restrict__ wfrag) {
    int i = blockIdx.x * 256 + threadIdx.x;
    if (i < NBUCK) bcursor[i] = i * CAP;
    if (i == 0) offs[N_NODES] = N_EDGES;
    if (i < 2048) {
        int lane  = i & 63;
        int tile  = (i >> 6) & 7;     // t*4+n
        int hl    = (i >> 9) & 1;
        int layer = (i >> 10) & 1;
        const float* W = layer ? W2 : W1;
        int kbase = (tile >> 2) * 32 + (lane >> 4) * 8;
        int j     = (tile & 3) * 16 + (lane & 15);
        unsigned p[4];
        #pragma unroll
        for (int e = 0; e < 8; e += 2) {
            float x0 = W[(kbase + e) * 64 + j];
            float x1 = W[(kbase + e + 1) * 64 + j];
            unsigned short u0, u1;
            if (hl == 0) {
                u0 = bf16_rne(x0);
                u1 = bf16_rne(x1);
            } else {
                unsigned short h0 = bf16_rne(x0);
                unsigned short h1 = bf16_rne(x1);
                u0 = bf16_rne(x0 - __uint_as_float((unsigned)h0 << 16));
                u1 = bf16_rne(x1 - __uint_as_float((unsigned)h1 << 16));
            }
            p[e >> 1] = (unsigned)u0 | ((unsigned)u1 << 16);
        }
        wfrag[i] = make_uint4(p[0], p[1], p[2], p[3]);
    }
}

// ---------------------------------------------------------------------------
// h -> bf16 conversion (halves agg gather bytes). 8 elems/thread.
// ---------------------------------------------------------------------------
__global__ __launch_bounds__(256) void h2bf16_kernel(const float* __restrict__ h,
                                                     unsigned short* __restrict__ hb) {
    int i = blockIdx.x * 256 + threadIdx.x;    // one per 8 elems
    if (i < N_NODES * 8) {
        const float4* p = (const float4*)(h + (size_t)i * 8);
        float4 a = p[0], b = p[1];
        unsigned u0 = (unsigned)bf16_rne(a.x) | ((unsigned)bf16_rne(a.y) << 16);
        unsigned u1 = (unsigned)bf16_rne(a.z) | ((unsigned)bf16_rne(a.w) << 16);
        unsigned u2 = (unsigned)bf16_rne(b.x) | ((unsigned)bf16_rne(b.y) << 16);
        unsigned u3 = (unsigned)bf16_rne(b.z) | ((unsigned)bf16_rne(b.w) << 16);
        *(uint4*)(hb + (size_t)i * 8) = make_uint4(u0, u1, u2, u3);
    }
}

// ---------------------------------------------------------------------------
// Partition into padded bucket staging (d_out). Block-chunked reservation.
// Record: {src | (dst_local<<17),  (log2fc_f16 << 16) | d_unorm16}
// ---------------------------------------------------------------------------
__global__ __launch_bounds__(1024) void partition_kernel(const int* __restrict__ dst,
                                                         const int* __restrict__ src,
                                                         const float* __restrict__ dist,
                                                         int* __restrict__ bcursor,
                                                         int2* __restrict__ brec) {
    __shared__ int hist[NBUCK];
    __shared__ int base_[NBUCK];
    int tid = threadIdx.x;
    for (int i = tid; i < NBUCK; i += 1024) hist[i] = 0;
    __syncthreads();

    int e0 = blockIdx.x * PCHUNK;
    int e1 = min(e0 + PCHUNK, N_EDGES);

    for (int t = e0 + tid; t < e1; t += 1024)
        atomicAdd(&hist[dst[t] >> BSHIFT], 1);
    __syncthreads();

    for (int i = tid; i < NBUCK; i += 1024) {
        int hv = hist[i];
        if (hv) base_[i] = atomicAdd(&bcursor[i], hv);
        hist[i] = 0;      // reuse as local cursor
    }
    __syncthreads();

    for (int t = e0 + tid; t < e1; t += 1024) {
        int d  = dst[t];
        int b  = d >> BSHIFT;
        int r  = atomicAdd(&hist[b], 1);
        float dv = dist[t];
        float fc = cutoff_fc(dv);
        float lfc = (fc > 0.0f) ? __log2f(fc) : -512.0f;
        unsigned dq = (unsigned)(fminf(fmaxf(dv, 0.0f), 1.0f) * 65535.0f + 0.5f);
        unsigned hf = (unsigned)__half_as_ushort(__float2half(lfc));
        int2 rec;
        rec.x = src[t] | ((d & (NPB - 1)) << 17);
        rec.y = (int)((hf << 16) | dq);
        brec[(size_t)base_[b] + r] = rec;
    }
}

// ---------------------------------------------------------------------------
// Compact scan: cnt[b] = bcursor[b]-b*CAP; boffs = exclusive scan.
// ---------------------------------------------------------------------------
__global__ __launch_bounds__(1024) void bscan_kernel(const int* __restrict__ bcursor,
                                                     int* __restrict__ boffs) {
    __shared__ int lds[1024];
    int tid = threadIdx.x;
    int v = (tid < NBUCK) ? (bcursor[tid] - tid * CAP) : 0;
    lds[tid] = v;
    __syncthreads();
    for (int off = 1; off < 1024; off <<= 1) {
        int x = (tid >= off) ? lds[tid - off] : 0;
        __syncthreads();
        lds[tid] += x;
        __syncthreads();
    }
    if (tid < NBUCK) boffs[tid] = lds[tid] - v;
    if (tid == 0) boffs[NBUCK] = N_EDGES;
}

// ---------------------------------------------------------------------------
// Node-sort v2: single global read. Stage bucket records in LDS, count,
// scan, scatter from LDS -> compact per-node CSR (rec_sorted, offs).
// ---------------------------------------------------------------------------
__global__ __launch_bounds__(256) void node_sort_kernel(const int2* __restrict__ brec,
                                                        const int* __restrict__ boffs,
                                                        int2* __restrict__ rec_sorted,
                                                        int* __restrict__ offs) {
    __shared__ int cntL[NPB];
    __shared__ int scanL[NPB];
    __shared__ int curL[NPB];
    __shared__ int2 stage[CAP];

    int b   = blockIdx.x;
    int tid = threadIdx.x;
    int beg = boffs[b];
    int cnt = boffs[b + 1] - beg;
    size_t pbase = (size_t)b * CAP;
    int node0 = b << BSHIFT;

    for (int i = tid; i < NPB; i += 256) cntL[i] = 0;
    __syncthreads();

    for (int t = tid; t < cnt; t += 256) {
        int2 r = brec[pbase + t];
        stage[t] = r;
        atomicAdd(&cntL[(r.x >> 17) & (NPB - 1)], 1);
    }
    __syncthreads();

    if (tid < NPB) scanL[tid] = cntL[tid];
    __syncthreads();
    for (int off = 1; off < NPB; off <<= 1) {
        int x = 0;
        if (tid < NPB && tid >= off) x = scanL[tid - off];
        __syncthreads();
        if (tid < NPB) scanL[tid] += x;
        __syncthreads();
    }
    if (tid < NPB) {
        int excl = scanL[tid] - cntL[tid];
        curL[tid] = excl;
        int node = node0 + tid;
        if (node < N_NODES) offs[node] = beg + excl;
    }
    __syncthreads();

    for (int t = tid; t < cnt; t += 256) {
        int2 r = stage[t];
        int dl = (r.x >> 17) & (NPB - 1);
        int p  = atomicAdd(&curL[dl], 1);
        rec_sorted[(size_t)beg + p] = r;
    }
}

// ---------------------------------------------------------------------------
// Aggregation v3 (bf16 h): one wave per node, lane k owns feature k.
// Cooperative record load: lane li loads ONE record of the 64-chunk
// (1 coalesced load per chunk), pre-converts its dK/lfc to f32 in parallel;
// the uniform j-loop broadcasts via 3 readlanes -> per record only
// {sub, fma, exp2, fma, shift} VALU + 1 gather.
// ---------------------------------------------------------------------------
__global__ __launch_bounds__(256) void agg_bf16_kernel(
    const unsigned short* __restrict__ hb,
    const int* __restrict__ offs,
    const int2* __restrict__ rec_sorted,
    float* __restrict__ out)
{
    int w    = threadIdx.x >> 6;
    int lane = threadIdx.x & 63;
    int node = blockIdx.x * 4 + w;
    if (node >= N_NODES) return;

    int beg = __builtin_amdgcn_readfirstlane(offs[node]);
    int end = __builtin_amdgcn_readfirstlane(offs[node + 1]);
    float muK  = (float)lane * (KSCALE / 63.0f);
    float acc0 = 0.0f, acc1 = 0.0f;

    for (int chunk = beg; chunk < end; chunk += 64) {
        int c = end - chunk;
        c = (c > 64) ? 64 : c;
        int li = (lane < c) ? lane : (c - 1);
        int2 myrec = rec_sorted[(size_t)chunk + li];
        int srcv = myrec.x & 0x1FFFF;
        unsigned ry = (unsigned)myrec.y;
        float dKv  = (float)(ry & 0xFFFFu) * (KSCALE / 65535.0f);
        float lfcv = __half2float(__ushort_as_half((unsigned short)(ry >> 16)));

#define REC3(J, ACC) { \
        int s_  = __builtin_amdgcn_readlane(srcv, (J)); \
        float dK_  = __int_as_float(__builtin_amdgcn_readlane(__float_as_int(dKv), (J))); \
        float lfc_ = __int_as_float(__builtin_amdgcn_readlane(__float_as_int(lfcv), (J))); \
        float hv_ = __uint_as_float((unsigned)hb[((size_t)s_ << 6) + lane] << 16); \
        float t_  = dK_ - muK; \
        float a_  = fmaf(-t_, t_, lfc_); \
        ACC = fmaf(hv_, exp2f(a_), ACC); }

        int j = 0;
        int cm = c & ~3;
        for (; j < cm; j += 4) {
            REC3(j + 0, acc0)
            REC3(j + 1, acc1)
            REC3(j + 2, acc0)
            REC3(j + 3, acc1)
        }
        for (; j < c; ++j) { REC3(j, acc0) }
#undef REC3
    }

    out[(size_t)node * 64 + lane] = acc0 + acc1;
}

// ---------------------------------------------------------------------------
// Aggregation (f32 h) — used when ws too small for the bf16 copy.
// ---------------------------------------------------------------------------
__global__ __launch_bounds__(256) void agg_kernel(
    const float* __restrict__ h,
    const int* __restrict__ offs,
    const int2* __restrict__ rec_sorted,
    float* __restrict__ out)
{
    int w    = threadIdx.x >> 6;
    int lane = threadIdx.x & 63;
    int node = blockIdx.x * 4 + w;
    if (node >= N_NODES) return;

    int beg = __builtin_amdgcn_readfirstlane(offs[node]);
    int end = __builtin_amdgcn_readfirstlane(offs[node + 1]);
    float muK = (float)lane * (KSCALE / 63.0f);
    float acc0 = 0.0f, acc1 = 0.0f;

#define REC(J, ACC) { \
        int2 r_ = rec_sorted[(size_t)(J)]; \
        int rx_ = __builtin_amdgcn_readfirstlane(r_.x); \
        unsigned ry_ = (unsigned)__builtin_amdgcn_readfirstlane(r_.y); \
        float hv_ = h[((size_t)(rx_ & 0x1FFFF) << 6) + lane]; \
        float dqf_ = (float)(ry_ & 0xFFFFu); \
        float lfc_ = __half2float(__ushort_as_half((unsigned short)(ry_ >> 16))); \
        float t_  = fmaf(dqf_, (KSCALE / 65535.0f), -muK); \
        float a_  = fmaf(-t_, t_, lfc_); \
        ACC = fmaf(hv_, exp2f(a_), ACC); }

    int i = beg;
    int main_end = beg + ((end - beg) & ~7);
    for (; i < main_end; i += 8) {
        REC(i + 0, acc0) REC(i + 1, acc1) REC(i + 2, acc0) REC(i + 3, acc1)
        REC(i + 4, acc0) REC(i + 5, acc1) REC(i + 6, acc0) REC(i + 7, acc1)
    }
    for (; i < end; ++i) { REC(i, acc0) }
#undef REC

    out[(size_t)node * 64 + lane] = acc0 + acc1;
}

// ---------------------------------------------------------------------------
// MLP v6 — MFMA. Per wave: 16 nodes. Split-bf16 3-pass.
// ---------------------------------------------------------------------------
__global__ __launch_bounds__(256) void mlp_kernel(
    float* __restrict__ io, const uint4* __restrict__ wfrag,
    const float* __restrict__ b1, const float* __restrict__ b2)
{
    __shared__ float hidL[4][16][68];

    int tid  = threadIdx.x;
    int lane = tid & 63;
    int wv   = tid >> 6;
    int grp  = blockIdx.x * 4 + wv;
    if (grp >= NGRP) return;
    int node0 = grp * 16;
    int lrow = lane & 15, lk = lane >> 4;

    const float* arow = io + (size_t)(node0 + lrow) * 64 + lk * 8;
    float4 t0 = *(const float4*)(arow);
    float4 t1 = *(const float4*)(arow + 4);
    float4 t2 = *(const float4*)(arow + 32);
    float4 t3 = *(const float4*)(arow + 36);
    short8_t Ah0, Al0, Ah1, Al1;
    split8(t0, t1, &Ah0, &Al0);
    split8(t2, t3, &Ah1, &Al1);

    f32x4_t acc[4];
    #pragma unroll
    for (int n = 0; n < 4; ++n) {
        float b = b1[n * 16 + lrow];
        acc[n] = (f32x4_t){b, b, b, b};
    }
    #pragma unroll
    for (int n = 0; n < 4; ++n) {
        short8_t wh0 = u4_to_s8(wfrag[(n) * 64 + lane]);
        short8_t wh1 = u4_to_s8(wfrag[(4 + n) * 64 + lane]);
        short8_t wl0 = u4_to_s8(wfrag[512 + n * 64 + lane]);
        short8_t wl1 = u4_to_s8(wfrag[512 + (4 + n) * 64 + lane]);
        f32x4_t c = acc[n];
        c = MFMA16(Ah0, wh0, c);
        c = MFMA16(Ah1, wh1, c);
        c = MFMA16(Ah0, wl0, c);
        c = MFMA16(Ah1, wl1, c);
        c = MFMA16(Al0, wh0, c);
        c = MFMA16(Al1, wh1, c);
        acc[n] = c;
    }

    #pragma unroll
    for (int n = 0; n < 4; ++n) {
        #pragma unroll
        for (int r = 0; r < 4; ++r) {
            float v = acc[n][r];
            float e = exp2f(v * 1.44269504089f);
            float sp = 0.69314718056f * __log2f(1.0f + e);
            v = (v > 20.0f) ? v : sp;
            hidL[wv][lk * 4 + r][n * 16 + lrow] = v;
        }
    }
    __threadfence_block();

    const float* hrow = &hidL[wv][lrow][lk * 8];
    float4 h0 = *(const float4*)(hrow);
    float4 h1 = *(const float4*)(hrow + 4);
    float4 h2 = *(const float4*)(hrow + 32);
    float4 h3 = *(const float4*)(hrow + 36);
    short8_t Bh0, Bl0, Bh1, Bl1;
    split8(h0, h1, &Bh0, &Bl0);
    split8(h2, h3, &Bh1, &Bl1);

    f32x4_t oac[4];
    #pragma unroll
    for (int n = 0; n < 4; ++n) {
        float b = b2[n * 16 + lrow];
        oac[n] = (f32x4_t){b, b, b, b};
    }
    #pragma unroll
    for (int n = 0; n < 4; ++n) {
        short8_t wh0 = u4_to_s8(wfrag[1024 + n * 64 + lane]);
        short8_t wh1 = u4_to_s8(wfrag[1024 + (4 + n) * 64 + lane]);
        short8_t wl0 = u4_to_s8(wfrag[1536 + n * 64 + lane]);
        short8_t wl1 = u4_to_s8(wfrag[1536 + (4 + n) * 64 + lane]);
        f32x4_t c = oac[n];
        c = MFMA16(Bh0, wh0, c);
        c = MFMA16(Bh1, wh1, c);
        c = MFMA16(Bh0, wl0, c);
        c = MFMA16(Bh1, wl1, c);
        c = MFMA16(Bl0, wh0, c);
        c = MFMA16(Bl1, wh1, c);
        oac[n] = c;
    }

    #pragma unroll
    for (int n = 0; n < 4; ++n) {
        #pragma unroll
        for (int r = 0; r < 4; ++r) {
            io[(size_t)(node0 + lk * 4 + r) * 64 + n * 16 + lrow] = oac[n][r];
        }
    }
}

// ---------------------------------------------------------------------------
// Fallback (ws too small): atomic scatter-add path + simple MLP.
// ---------------------------------------------------------------------------
__global__ __launch_bounds__(256) void schnet_edge_kernel(
    const float* __restrict__ h,
    const float* __restrict__ dist,
    const int* __restrict__ src_idx,
    const int* __restrict__ dst_idx,
    float* __restrict__ agg)
{
    long long idx = (long long)blockIdx.x * 256 + threadIdx.x;
    int e = (int)(idx >> 6);
    if (e >= N_EDGES) return;
    int k = (int)(idx & 63);
    float d = dist[e];
    float c = edge_coef(d, (float)k * (1.0f / 63.0f));
    int s  = src_idx[e];
    int dn = dst_idx[e];
    atomicAdd(&agg[(long long)dn * 64 + k], h[(long long)s * 64 + k] * c);
}

__global__ __launch_bounds__(256) void mlp_fallback_kernel(
    float* __restrict__ io,
    const float* __restrict__ W1, const float* __restrict__ b1,
    const float* __restrict__ W2, const float* __restrict__ b2)
{
    __shared__ float sW1[64 * 64];
    __shared__ float sW2[64 * 64];
    __shared__ float sRow[4][64];
    __shared__ float sHid[4][64];
    int tid = threadIdx.x;
    for (int i = tid; i < 4096; i += 256) { sW1[i] = W1[i]; sW2[i] = W2[i]; }
    __syncthreads();
    int lane = tid & 63, w = tid >> 6;
    float bb1 = b1[lane], bb2 = b2[lane];
    for (int base = blockIdx.x * 4; base < N_NODES; base += gridDim.x * 4) {
        int node = base + w;
        if (node < N_NODES) sRow[w][lane] = io[(size_t)node * 64 + lane];
        __syncthreads();
        float a = bb1;
        #pragma unroll
        for (int k = 0; k < 64; ++k) a = fmaf(sRow[w][k], sW1[k * 64 + lane], a);
        sHid[w][lane] = (a > 20.f) ? a : log1pf(__expf(a));
        __syncthreads();
        float c = bb2;
        #pragma unroll
        for (int k = 0; k < 64; ++k) c = fmaf(sHid[w][k], sW2[k * 64 + lane], c);
        if (node < N_NODES) io[(size_t)node * 64 + lane] = c;
        __syncthreads();
    }
}

extern "C" void kernel_launch(void* const* d_in, const int* in_sizes, int n_in,
                              void* d_out, int out_size, void* d_ws, size_t ws_size,
                              hipStream_t stream) {
    const float* h    = (const float*)d_in[0];
    const float* dist = (const float*)d_in[1];
    const float* W1   = (const float*)d_in[2];
    const float* b1   = (const float*)d_in[3];
    const float* W2   = (const float*)d_in[4];
    const float* b2   = (const float*)d_in[5];
    const int* src    = (const int*)d_in[6];
    const int* dst    = (const int*)d_in[7];
    float* out        = (float*)d_out;

    // ws layout (bytes): wfrag 32KB | [hb 12.8MB bf16 path] | rec_sorted 12.8MB |
    //                    boffs[NBUCK+1] | bcursor[NBUCK] | offs[N+1]
    const size_t WFRAG_B = 32768;
    const size_t HB_B    = (size_t)N_NODES * 64 * 2;           // 12.8 MB
    const size_t RS_B    = (size_t)N_EDGES * 8;                // 12.8 MB
    const size_t INTS_B  = ((size_t)NBUCK + 1 + NBUCK + N_NODES + 1) * 4;
    size_t need_f32  = WFRAG_B + RS_B + INTS_B;
    size_t need_bf16 = WFRAG_B + HB_B + RS_B + INTS_B;

    if (ws_size >= need_f32) {
        bool use_bf16 = (ws_size >= need_bf16);
        char* p = (char*)d_ws;
        uint4* wfrag = (uint4*)p;              p += WFRAG_B;
        unsigned short* hb = (unsigned short*)p;
        if (use_bf16)                          p += HB_B;
        int2* rec_sorted = (int2*)p;           p += RS_B;
        int* boffs   = (int*)p;                // NBUCK+1
        int* bcursor = boffs + NBUCK + 1;
        int* offs    = bcursor + NBUCK;        // N+1

        // padded bucket staging in d_out (782*4088 recs = 25.57MB <= 25.6MB)
        int2* brec = (int2*)d_out;

        init_kernel<<<16, 256, 0, stream>>>(bcursor, offs, W1, W2, wfrag);
        if (use_bf16)
            h2bf16_kernel<<<(N_NODES * 8 + 255) / 256, 256, 0, stream>>>(h, hb);
        partition_kernel<<<PGRID, 1024, 0, stream>>>(dst, src, dist, bcursor, brec);
        bscan_kernel<<<1, 1024, 0, stream>>>(bcursor, boffs);
        node_sort_kernel<<<NBUCK, 256, 0, stream>>>(brec, boffs, rec_sorted, offs);
        if (use_bf16)
            agg_bf16_kernel<<<N_NODES / 4, 256, 0, stream>>>(hb, offs, rec_sorted, out);
        else
            agg_kernel<<<N_NODES / 4, 256, 0, stream>>>(h, offs, rec_sorted, out);
        mlp_kernel<<<(NGRP + 3) / 4, 256, 0, stream>>>(out, wfrag, b1, b2);
    } else {
        hipMemsetAsync(out, 0, (size_t)N_NODES * IN_FEATS * sizeof(float), stream);
        long long total = (long long)N_EDGES * 64;
        schnet_edge_kernel<<<(int)((total + 255) / 256), 256, 0, stream>>>(
            h, dist, src, dst, out);
        mlp_fallback_kernel<<<2048, 256, 0, stream>>>(out, W1, b1, W2, b2);
    }
}

// Round 20
// 116.799 us; speedup vs baseline: 1.1064x; 1.0870x over previous
//
#include <hip/hip_runtime.h>
#include <hip/hip_fp16.h>
#include <math.h>

#define IN_FEATS 64
#define N_NODES 100000
#define N_EDGES 1600000
#define BSHIFT 7
#define NPB 128                              // nodes per bucket
#define NBUCK ((N_NODES + NPB - 1) / NPB)    // 782
#define CAP 4088                             // padded bucket capacity (mean 2046, sigma 45)
#define PCHUNK 8192
#define PGRID ((N_EDGES + PCHUNK - 1) / PCHUNK)  // 196
#define NGRP (N_NODES / 16)                  // 6250 (exact)

// sqrt(64 * log2(e)) : exp(-64 t^2) == exp2(-((K t))^2)
#define KSCALE 9.6089785f

typedef __attribute__((ext_vector_type(8))) short short8_t;
typedef __attribute__((ext_vector_type(4))) float f32x4_t;

#define MFMA16(a, b, c) __builtin_amdgcn_mfma_f32_16x16x32_bf16(a, b, c, 0, 0, 0)

__device__ __forceinline__ unsigned short bf16_rne(float x) {
    unsigned u = __float_as_uint(x);
    unsigned r = u + 0x7FFFu + ((u >> 16) & 1u);
    return (unsigned short)(r >> 16);
}

__device__ __forceinline__ short8_t u4_to_s8(uint4 v) {
    union { uint4 u; short8_t s; } cv; cv.u = v; return cv.s;
}

// split 8 f32 (two float4) into hi/lo bf16 fragments
__device__ __forceinline__ void split8(float4 a, float4 b,
                                       short8_t* hi, short8_t* lo) {
    short8_t h, l;
#define SP(I, X) { unsigned short hu = bf16_rne(X); \
        float hf = __uint_as_float((unsigned)hu << 16); \
        unsigned short lu = bf16_rne((X) - hf); \
        h[I] = (short)hu; l[I] = (short)lu; }
    SP(0, a.x) SP(1, a.y) SP(2, a.z) SP(3, a.w)
    SP(4, b.x) SP(5, b.y) SP(6, b.z) SP(7, b.w)
#undef SP
    *hi = h; *lo = l;
}

// ---------------------------------------------------------------------------
// full edge coefficient (fallback path only)
// ---------------------------------------------------------------------------
__device__ __forceinline__ float edge_coef(float d, float mu) {
    float t = d - mu;
    float rbf = __expf(-64.0f * t * t);
    float x  = (d - 0.8f) * 5.0f;
    float xc = fminf(fmaxf(x, 0.0f), 1.0f);
    float ramp = 0.5f * (__cosf(3.14159265358979323846f * xc) + 1.0f);
    float fc = (d <= 0.8f) ? 1.0f : ((d >= 1.0f) ? 0.0f : ramp);
    return rbf * fc;
}

__device__ __forceinline__ float cutoff_fc(float d) {
    float x  = (d - 0.8f) * 5.0f;
    float xc = fminf(fmaxf(x, 0.0f), 1.0f);
    float ramp = 0.5f * (__cosf(3.14159265358979323846f * xc) + 1.0f);
    return (d <= 0.8f) ? 1.0f : ((d >= 1.0f) ? 0.0f : ramp);
}

// ---------------------------------------------------------------------------
// Init (fused): bcursor, sentinel, wfrag tables, AND h->bf16 conversion.
// Grid 3136 blocks x 256.
// ---------------------------------------------------------------------------
__global__ __launch_bounds__(256) void init_kernel(int* __restrict__ bcursor,
                                                   int* __restrict__ offs,
                                                   const float* __restrict__ W1,
                                                   const float* __restrict__ W2,
                                                   uint4* __restrict__ wfrag,
                                                   const float* __restrict__ h,
                                                   unsigned short* __restrict__ hb) {
    int i = blockIdx.x * 256 + threadIdx.x;
    if (i < NBUCK) bcursor[i] = i * CAP;
    if (i == 0) offs[N_NODES] = N_EDGES;
    if (i < 2048) {
        int lane  = i & 63;
        int tile  = (i >> 6) & 7;     // t*4+n
        int hl    = (i >> 9) & 1;
        int layer = (i >> 10) & 1;
        const float* W = layer ? W2 : W1;
        int kbase = (tile >> 2) * 32 + (lane >> 4) * 8;
        int j     = (tile & 3) * 16 + (lane & 15);
        unsigned p[4];
        #pragma unroll
        for (int e = 0; e < 8; e += 2) {
            float x0 = W[(kbase + e) * 64 + j];
            float x1 = W[(kbase + e + 1) * 64 + j];
            unsigned short u0, u1;
            if (hl == 0) {
                u0 = bf16_rne(x0);
                u1 = bf16_rne(x1);
            } else {
                unsigned short h0 = bf16_rne(x0);
                unsigned short h1 = bf16_rne(x1);
                u0 = bf16_rne(x0 - __uint_as_float((unsigned)h0 << 16));
                u1 = bf16_rne(x1 - __uint_as_float((unsigned)h1 << 16));
            }
            p[e >> 1] = (unsigned)u0 | ((unsigned)u1 << 16);
        }
        wfrag[i] = make_uint4(p[0], p[1], p[2], p[3]);
    }
    if (i < N_NODES * 8) {
        const float4* p = (const float4*)(h + (size_t)i * 8);
        float4 a = p[0], b = p[1];
        unsigned u0 = (unsigned)bf16_rne(a.x) | ((unsigned)bf16_rne(a.y) << 16);
        unsigned u1 = (unsigned)bf16_rne(a.z) | ((unsigned)bf16_rne(a.w) << 16);
        unsigned u2 = (unsigned)bf16_rne(b.x) | ((unsigned)bf16_rne(b.y) << 16);
        unsigned u3 = (unsigned)bf16_rne(b.z) | ((unsigned)bf16_rne(b.w) << 16);
        *(uint4*)(hb + (size_t)i * 8) = make_uint4(u0, u1, u2, u3);
    }
}

// ---------------------------------------------------------------------------
// Partition into padded bucket staging (d_out). Block-chunked reservation.
// Record: {src | (dst_local<<17),  (log2fc_f16 << 16) | d_unorm16}
// ---------------------------------------------------------------------------
__global__ __launch_bounds__(1024) void partition_kernel(const int* __restrict__ dst,
                                                         const int* __restrict__ src,
                                                         const float* __restrict__ dist,
                                                         int* __restrict__ bcursor,
                                                         int2* __restrict__ brec) {
    __shared__ int hist[NBUCK];
    __shared__ int base_[NBUCK];
    int tid = threadIdx.x;
    for (int i = tid; i < NBUCK; i += 1024) hist[i] = 0;
    __syncthreads();

    int e0 = blockIdx.x * PCHUNK;
    int e1 = min(e0 + PCHUNK, N_EDGES);

    for (int t = e0 + tid; t < e1; t += 1024)
        atomicAdd(&hist[dst[t] >> BSHIFT], 1);
    __syncthreads();

    for (int i = tid; i < NBUCK; i += 1024) {
        int hv = hist[i];
        if (hv) base_[i] = atomicAdd(&bcursor[i], hv);
        hist[i] = 0;      // reuse as local cursor
    }
    __syncthreads();

    for (int t = e0 + tid; t < e1; t += 1024) {
        int d  = dst[t];
        int b  = d >> BSHIFT;
        int r  = atomicAdd(&hist[b], 1);
        float dv = dist[t];
        float fc = cutoff_fc(dv);
        float lfc = (fc > 0.0f) ? __log2f(fc) : -512.0f;
        unsigned dq = (unsigned)(fminf(fmaxf(dv, 0.0f), 1.0f) * 65535.0f + 0.5f);
        unsigned hf = (unsigned)__half_as_ushort(__float2half(lfc));
        int2 rec;
        rec.x = src[t] | ((d & (NPB - 1)) << 17);
        rec.y = (int)((hf << 16) | dq);
        brec[(size_t)base_[b] + r] = rec;
    }
}

// ---------------------------------------------------------------------------
// Compact scan: cnt[b] = bcursor[b]-b*CAP; boffs = exclusive scan.
// ---------------------------------------------------------------------------
__global__ __launch_bounds__(1024) void bscan_kernel(const int* __restrict__ bcursor,
                                                     int* __restrict__ boffs) {
    __shared__ int lds[1024];
    int tid = threadIdx.x;
    int v = (tid < NBUCK) ? (bcursor[tid] - tid * CAP) : 0;
    lds[tid] = v;
    __syncthreads();
    for (int off = 1; off < 1024; off <<= 1) {
        int x = (tid >= off) ? lds[tid - off] : 0;
        __syncthreads();
        lds[tid] += x;
        __syncthreads();
    }
    if (tid < NBUCK) boffs[tid] = lds[tid] - v;
    if (tid == 0) boffs[NBUCK] = N_EDGES;
}

// ---------------------------------------------------------------------------
// Node-sort: single global read. Stage bucket records in LDS, count,
// scan, scatter from LDS -> compact per-node CSR (rec_sorted, offs).
// ---------------------------------------------------------------------------
__global__ __launch_bounds__(256) void node_sort_kernel(const int2* __restrict__ brec,
                                                        const int* __restrict__ boffs,
                                                        int2* __restrict__ rec_sorted,
                                                        int* __restrict__ offs) {
    __shared__ int cntL[NPB];
    __shared__ int scanL[NPB];
    __shared__ int curL[NPB];
    __shared__ int2 stage[CAP];

    int b   = blockIdx.x;
    int tid = threadIdx.x;
    int beg = boffs[b];
    int cnt = boffs[b + 1] - beg;
    size_t pbase = (size_t)b * CAP;
    int node0 = b << BSHIFT;

    for (int i = tid; i < NPB; i += 256) cntL[i] = 0;
    __syncthreads();

    for (int t = tid; t < cnt; t += 256) {
        int2 r = brec[pbase + t];
        stage[t] = r;
        atomicAdd(&cntL[(r.x >> 17) & (NPB - 1)], 1);
    }
    __syncthreads();

    if (tid < NPB) scanL[tid] = cntL[tid];
    __syncthreads();
    for (int off = 1; off < NPB; off <<= 1) {
        int x = 0;
        if (tid < NPB && tid >= off) x = scanL[tid - off];
        __syncthreads();
        if (tid < NPB) scanL[tid] += x;
        __syncthreads();
    }
    if (tid < NPB) {
        int excl = scanL[tid] - cntL[tid];
        curL[tid] = excl;
        int node = node0 + tid;
        if (node < N_NODES) offs[node] = beg + excl;
    }
    __syncthreads();

    for (int t = tid; t < cnt; t += 256) {
        int2 r = stage[t];
        int dl = (r.x >> 17) & (NPB - 1);
        int p  = atomicAdd(&curL[dl], 1);
        rec_sorted[(size_t)beg + p] = r;
    }
}

// ---------------------------------------------------------------------------
// Aggregation (bf16 h, round-18 proven inner loop): one wave per node,
// lane k owns feature k. Uniform record load + readfirstlane/SALU unpack,
// coef = exp2(lfc - t^2), 8x unroll, 2 acc chains.
// ---------------------------------------------------------------------------
__global__ __launch_bounds__(256) void agg_bf16_kernel(
    const unsigned short* __restrict__ hb,
    const int* __restrict__ offs,
    const int2* __restrict__ rec_sorted,
    float* __restrict__ out)
{
    int w    = threadIdx.x >> 6;
    int lane = threadIdx.x & 63;
    int node = blockIdx.x * 4 + w;
    if (node >= N_NODES) return;

    int beg = __builtin_amdgcn_readfirstlane(offs[node]);
    int end = __builtin_amdgcn_readfirstlane(offs[node + 1]);
    float muK = (float)lane * (KSCALE / 63.0f);
    float acc0 = 0.0f, acc1 = 0.0f;

#define REC(J, ACC) { \
        int2 r_ = rec_sorted[(size_t)(J)]; \
        int rx_ = __builtin_amdgcn_readfirstlane(r_.x); \
        unsigned ry_ = (unsigned)__builtin_amdgcn_readfirstlane(r_.y); \
        unsigned hvu_ = (unsigned)hb[((size_t)(rx_ & 0x1FFFF) << 6) + lane]; \
        float hv_ = __uint_as_float(hvu_ << 16); \
        float dqf_ = (float)(ry_ & 0xFFFFu); \
        float lfc_ = __half2float(__ushort_as_half((unsigned short)(ry_ >> 16))); \
        float t_  = fmaf(dqf_, (KSCALE / 65535.0f), -muK); \
        float a_  = fmaf(-t_, t_, lfc_); \
        ACC = fmaf(hv_, exp2f(a_), ACC); }

    int i = beg;
    int main_end = beg + ((end - beg) & ~7);
    for (; i < main_end; i += 8) {
        REC(i + 0, acc0) REC(i + 1, acc1) REC(i + 2, acc0) REC(i + 3, acc1)
        REC(i + 4, acc0) REC(i + 5, acc1) REC(i + 6, acc0) REC(i + 7, acc1)
    }
    for (; i < end; ++i) { REC(i, acc0) }
#undef REC

    out[(size_t)node * 64 + lane] = acc0 + acc1;
}

// ---------------------------------------------------------------------------
// Aggregation (f32 h) — used when ws too small for the bf16 copy.
// ---------------------------------------------------------------------------
__global__ __launch_bounds__(256) void agg_kernel(
    const float* __restrict__ h,
    const int* __restrict__ offs,
    const int2* __restrict__ rec_sorted,
    float* __restrict__ out)
{
    int w    = threadIdx.x >> 6;
    int lane = threadIdx.x & 63;
    int node = blockIdx.x * 4 + w;
    if (node >= N_NODES) return;

    int beg = __builtin_amdgcn_readfirstlane(offs[node]);
    int end = __builtin_amdgcn_readfirstlane(offs[node + 1]);
    float muK = (float)lane * (KSCALE / 63.0f);
    float acc0 = 0.0f, acc1 = 0.0f;

#define REC(J, ACC) { \
        int2 r_ = rec_sorted[(size_t)(J)]; \
        int rx_ = __builtin_amdgcn_readfirstlane(r_.x); \
        unsigned ry_ = (unsigned)__builtin_amdgcn_readfirstlane(r_.y); \
        float hv_ = h[((size_t)(rx_ & 0x1FFFF) << 6) + lane]; \
        float dqf_ = (float)(ry_ & 0xFFFFu); \
        float lfc_ = __half2float(__ushort_as_half((unsigned short)(ry_ >> 16))); \
        float t_  = fmaf(dqf_, (KSCALE / 65535.0f), -muK); \
        float a_  = fmaf(-t_, t_, lfc_); \
        ACC = fmaf(hv_, exp2f(a_), ACC); }

    int i = beg;
    int main_end = beg + ((end - beg) & ~7);
    for (; i < main_end; i += 8) {
        REC(i + 0, acc0) REC(i + 1, acc1) REC(i + 2, acc0) REC(i + 3, acc1)
        REC(i + 4, acc0) REC(i + 5, acc1) REC(i + 6, acc0) REC(i + 7, acc1)
    }
    for (; i < end; ++i) { REC(i, acc0) }
#undef REC

    out[(size_t)node * 64 + lane] = acc0 + acc1;
}

// ---------------------------------------------------------------------------
// MLP — MFMA. Per wave: 16 nodes. Split-bf16 3-pass.
// ---------------------------------------------------------------------------
__global__ __launch_bounds__(256) void mlp_kernel(
    float* __restrict__ io, const uint4* __restrict__ wfrag,
    const float* __restrict__ b1, const float* __restrict__ b2)
{
    __shared__ float hidL[4][16][68];

    int tid  = threadIdx.x;
    int lane = tid & 63;
    int wv   = tid >> 6;
    int grp  = blockIdx.x * 4 + wv;
    if (grp >= NGRP) return;
    int node0 = grp * 16;
    int lrow = lane & 15, lk = lane >> 4;

    const float* arow = io + (size_t)(node0 + lrow) * 64 + lk * 8;
    float4 t0 = *(const float4*)(arow);
    float4 t1 = *(const float4*)(arow + 4);
    float4 t2 = *(const float4*)(arow + 32);
    float4 t3 = *(const float4*)(arow + 36);
    short8_t Ah0, Al0, Ah1, Al1;
    split8(t0, t1, &Ah0, &Al0);
    split8(t2, t3, &Ah1, &Al1);

    f32x4_t acc[4];
    #pragma unroll
    for (int n = 0; n < 4; ++n) {
        float b = b1[n * 16 + lrow];
        acc[n] = (f32x4_t){b, b, b, b};
    }
    #pragma unroll
    for (int n = 0; n < 4; ++n) {
        short8_t wh0 = u4_to_s8(wfrag[(n) * 64 + lane]);
        short8_t wh1 = u4_to_s8(wfrag[(4 + n) * 64 + lane]);
        short8_t wl0 = u4_to_s8(wfrag[512 + n * 64 + lane]);
        short8_t wl1 = u4_to_s8(wfrag[512 + (4 + n) * 64 + lane]);
        f32x4_t c = acc[n];
        c = MFMA16(Ah0, wh0, c);
        c = MFMA16(Ah1, wh1, c);
        c = MFMA16(Ah0, wl0, c);
        c = MFMA16(Ah1, wl1, c);
        c = MFMA16(Al0, wh0, c);
        c = MFMA16(Al1, wh1, c);
        acc[n] = c;
    }

    #pragma unroll
    for (int n = 0; n < 4; ++n) {
        #pragma unroll
        for (int r = 0; r < 4; ++r) {
            float v = acc[n][r];
            float e = exp2f(v * 1.44269504089f);
            float sp = 0.69314718056f * __log2f(1.0f + e);
            v = (v > 20.0f) ? v : sp;
            hidL[wv][lk * 4 + r][n * 16 + lrow] = v;
        }
    }
    __threadfence_block();

    const float* hrow = &hidL[wv][lrow][lk * 8];
    float4 h0 = *(const float4*)(hrow);
    float4 h1 = *(const float4*)(hrow + 4);
    float4 h2 = *(const float4*)(hrow + 32);
    float4 h3 = *(const float4*)(hrow + 36);
    short8_t Bh0, Bl0, Bh1, Bl1;
    split8(h0, h1, &Bh0, &Bl0);
    split8(h2, h3, &Bh1, &Bl1);

    f32x4_t oac[4];
    #pragma unroll
    for (int n = 0; n < 4; ++n) {
        float b = b2[n * 16 + lrow];
        oac[n] = (f32x4_t){b, b, b, b};
    }
    #pragma unroll
    for (int n = 0; n < 4; ++n) {
        short8_t wh0 = u4_to_s8(wfrag[1024 + n * 64 + lane]);
        short8_t wh1 = u4_to_s8(wfrag[1024 + (4 + n) * 64 + lane]);
        short8_t wl0 = u4_to_s8(wfrag[1536 + n * 64 + lane]);
        short8_t wl1 = u4_to_s8(wfrag[1536 + (4 + n) * 64 + lane]);
        f32x4_t c = oac[n];
        c = MFMA16(Bh0, wh0, c);
        c = MFMA16(Bh1, wh1, c);
        c = MFMA16(Bh0, wl0, c);
        c = MFMA16(Bh1, wl1, c);
        c = MFMA16(Bl0, wh0, c);
        c = MFMA16(Bl1, wh1, c);
        oac[n] = c;
    }

    #pragma unroll
    for (int n = 0; n < 4; ++n) {
        #pragma unroll
        for (int r = 0; r < 4; ++r) {
            io[(size_t)(node0 + lk * 4 + r) * 64 + n * 16 + lrow] = oac[n][r];
        }
    }
}

// ---------------------------------------------------------------------------
// Fallback (ws too small): atomic scatter-add path + simple MLP.
// ---------------------------------------------------------------------------
__global__ __launch_bounds__(256) void schnet_edge_kernel(
    const float* __restrict__ h,
    const float* __restrict__ dist,
    const int* __restrict__ src_idx,
    const int* __restrict__ dst_idx,
    float* __restrict__ agg)
{
    long long idx = (long long)blockIdx.x * 256 + threadIdx.x;
    int e = (int)(idx >> 6);
    if (e >= N_EDGES) return;
    int k = (int)(idx & 63);
    float d = dist[e];
    float c = edge_coef(d, (float)k * (1.0f / 63.0f));
    int s  = src_idx[e];
    int dn = dst_idx[e];
    atomicAdd(&agg[(long long)dn * 64 + k], h[(long long)s * 64 + k] * c);
}

__global__ __launch_bounds__(256) void mlp_fallback_kernel(
    float* __restrict__ io,
    const float* __restrict__ W1, const float* __restrict__ b1,
    const float* __restrict__ W2, const float* __restrict__ b2)
{
    __shared__ float sW1[64 * 64];
    __shared__ float sW2[64 * 64];
    __shared__ float sRow[4][64];
    __shared__ float sHid[4][64];
    int tid = threadIdx.x;
    for (int i = tid; i < 4096; i += 256) { sW1[i] = W1[i]; sW2[i] = W2[i]; }
    __syncthreads();
    int lane = tid & 63, w = tid >> 6;
    float bb1 = b1[lane], bb2 = b2[lane];
    for (int base = blockIdx.x * 4; base < N_NODES; base += gridDim.x * 4) {
        int node = base + w;
        if (node < N_NODES) sRow[w][lane] = io[(size_t)node * 64 + lane];
        __syncthreads();
        float a = bb1;
        #pragma unroll
        for (int k = 0; k < 64; ++k) a = fmaf(sRow[w][k], sW1[k * 64 + lane], a);
        sHid[w][lane] = (a > 20.f) ? a : log1pf(__expf(a));
        __syncthreads();
        float c = bb2;
        #pragma unroll
        for (int k = 0; k < 64; ++k) c = fmaf(sHid[w][k], sW2[k * 64 + lane], c);
        if (node < N_NODES) io[(size_t)node * 64 + lane] = c;
        __syncthreads();
    }
}

extern "C" void kernel_launch(void* const* d_in, const int* in_sizes, int n_in,
                              void* d_out, int out_size, void* d_ws, size_t ws_size,
                              hipStream_t stream) {
    const float* h    = (const float*)d_in[0];
    const float* dist = (const float*)d_in[1];
    const float* W1   = (const float*)d_in[2];
    const float* b1   = (const float*)d_in[3];
    const float* W2   = (const float*)d_in[4];
    const float* b2   = (const float*)d_in[5];
    const int* src    = (const int*)d_in[6];
    const int* dst    = (const int*)d_in[7];
    float* out        = (float*)d_out;

    // ws layout (bytes): wfrag 32KB | [hb 12.8MB bf16 path] | rec_sorted 12.8MB |
    //                    boffs[NBUCK+1] | bcursor[NBUCK] | offs[N+1]
    const size_t WFRAG_B = 32768;
    const size_t HB_B    = (size_t)N_NODES * 64 * 2;           // 12.8 MB
    const size_t RS_B    = (size_t)N_EDGES * 8;                // 12.8 MB
    const size_t INTS_B  = ((size_t)NBUCK + 1 + NBUCK + N_NODES + 1) * 4;
    size_t need_f32  = WFRAG_B + RS_B + INTS_B;
    size_t need_bf16 = WFRAG_B + HB_B + RS_B + INTS_B;

    if (ws_size >= need_f32) {
        bool use_bf16 = (ws_size >= need_bf16);
        char* p = (char*)d_ws;
        uint4* wfrag = (uint4*)p;              p += WFRAG_B;
        unsigned short* hb = (unsigned short*)p;
        if (use_bf16)                          p += HB_B;
        int2* rec_sorted = (int2*)p;           p += RS_B;
        int* boffs   = (int*)p;                // NBUCK+1
        int* bcursor = boffs + NBUCK + 1;
        int* offs    = bcursor + NBUCK;        // N+1

        // padded bucket staging in d_out (782*4088 recs = 25.57MB <= 25.6MB)
        int2* brec = (int2*)d_out;

        int init_grid = use_bf16 ? (N_NODES * 8 + 255) / 256 : 16;
        init_kernel<<<init_grid, 256, 0, stream>>>(bcursor, offs, W1, W2, wfrag,
                                                   h, use_bf16 ? hb : nullptr);
        partition_kernel<<<PGRID, 1024, 0, stream>>>(dst, src, dist, bcursor, brec);
        bscan_kernel<<<1, 1024, 0, stream>>>(bcursor, boffs);
        node_sort_kernel<<<NBUCK, 256, 0, stream>>>(brec, boffs, rec_sorted, offs);
        if (use_bf16)
            agg_bf16_kernel<<<N_NODES / 4, 256, 0, stream>>>(hb, offs, rec_sorted, out);
        else
            agg_kernel<<<N_NODES / 4, 256, 0, stream>>>(h, offs, rec_sorted, out);
        mlp_kernel<<<(NGRP + 3) / 4, 256, 0, stream>>>(out, wfrag, b1, b2);
    } else {
        hipMemsetAsync(out, 0, (size_t)N_NODES * IN_FEATS * sizeof(float), stream);
        long long total = (long long)N_EDGES * 64;
        schnet_edge_kernel<<<(int)((total + 255) / 256), 256, 0, stream>>>(
            h, dist, src, dst, out);
        mlp_fallback_kernel<<<2048, 256, 0, stream>>>(out, W1, b1, W2, b2);
    }
}

// Round 21
// 112.249 us; speedup vs baseline: 1.1512x; 1.0405x over previous
//
#include <hip/hip_runtime.h>
#include <hip/hip_fp16.h>
#include <math.h>

#define IN_FEATS 64
#define N_NODES 100000
#define N_EDGES 1600000
#define BSHIFT 7
#define NPB 128                              // nodes per bucket
#define NBUCK ((N_NODES + NPB - 1) / NPB)    // 782
#define CAP 4088                             // padded bucket capacity (mean 2046, sigma 45)
#define PCHUNK 8192
#define PGRID ((N_EDGES + PCHUNK - 1) / PCHUNK)  // 196
#define HBLK ((N_NODES * 8 + 1023) / 1024)   // 782 conversion blocks
#define NGRP (N_NODES / 16)                  // 6250 (exact)
#define EPT (PCHUNK / 1024)                  // 8 edges per thread

// sqrt(64 * log2(e)) : exp(-64 t^2) == exp2(-((K t))^2)
#define KSCALE 9.6089785f

typedef __attribute__((ext_vector_type(8))) short short8_t;
typedef __attribute__((ext_vector_type(4))) float f32x4_t;

#define MFMA16(a, b, c) __builtin_amdgcn_mfma_f32_16x16x32_bf16(a, b, c, 0, 0, 0)

__device__ __forceinline__ unsigned short bf16_rne(float x) {
    unsigned u = __float_as_uint(x);
    unsigned r = u + 0x7FFFu + ((u >> 16) & 1u);
    return (unsigned short)(r >> 16);
}

__device__ __forceinline__ short8_t u4_to_s8(uint4 v) {
    union { uint4 u; short8_t s; } cv; cv.u = v; return cv.s;
}

// split 8 f32 (two float4) into hi/lo bf16 fragments
__device__ __forceinline__ void split8(float4 a, float4 b,
                                       short8_t* hi, short8_t* lo) {
    short8_t h, l;
#define SP(I, X) { unsigned short hu = bf16_rne(X); \
        float hf = __uint_as_float((unsigned)hu << 16); \
        unsigned short lu = bf16_rne((X) - hf); \
        h[I] = (short)hu; l[I] = (short)lu; }
    SP(0, a.x) SP(1, a.y) SP(2, a.z) SP(3, a.w)
    SP(4, b.x) SP(5, b.y) SP(6, b.z) SP(7, b.w)
#undef SP
    *hi = h; *lo = l;
}

// ---------------------------------------------------------------------------
// full edge coefficient (fallback path only)
// ---------------------------------------------------------------------------
__device__ __forceinline__ float edge_coef(float d, float mu) {
    float t = d - mu;
    float rbf = __expf(-64.0f * t * t);
    float x  = (d - 0.8f) * 5.0f;
    float xc = fminf(fmaxf(x, 0.0f), 1.0f);
    float ramp = 0.5f * (__cosf(3.14159265358979323846f * xc) + 1.0f);
    float fc = (d <= 0.8f) ? 1.0f : ((d >= 1.0f) ? 0.0f : ramp);
    return rbf * fc;
}

__device__ __forceinline__ float cutoff_fc(float d) {
    float x  = (d - 0.8f) * 5.0f;
    float xc = fminf(fmaxf(x, 0.0f), 1.0f);
    float ramp = 0.5f * (__cosf(3.14159265358979323846f * xc) + 1.0f);
    return (d <= 0.8f) ? 1.0f : ((d >= 1.0f) ? 0.0f : ramp);
}

// ---------------------------------------------------------------------------
// Init: bcursor, offs sentinel, wfrag MFMA tables (hi/lo bf16 of W1/W2).
// ---------------------------------------------------------------------------
__global__ __launch_bounds__(256) void init_kernel(int* __restrict__ bcursor,
                                                   int* __restrict__ offs,
                                                   const float* __restrict__ W1,
                                                   const float* __restrict__ W2,
                                                   uint4* __restrict__ wfrag) {
    int i = blockIdx.x * 256 + threadIdx.x;
    if (i < NBUCK) bcursor[i] = i * CAP;
    if (i == 0) offs[N_NODES] = N_EDGES;
    if (i < 2048) {
        int lane  = i & 63;
        int tile  = (i >> 6) & 7;     // t*4+n
        int hl    = (i >> 9) & 1;
        int layer = (i >> 10) & 1;
        const float* W = layer ? W2 : W1;
        int kbase = (tile >> 2) * 32 + (lane >> 4) * 8;
        int j     = (tile & 3) * 16 + (lane & 15);
        unsigned p[4];
        #pragma unroll
        for (int e = 0; e < 8; e += 2) {
            float x0 = W[(kbase + e) * 64 + j];
            float x1 = W[(kbase + e + 1) * 64 + j];
            unsigned short u0, u1;
            if (hl == 0) {
                u0 = bf16_rne(x0);
                u1 = bf16_rne(x1);
            } else {
                unsigned short h0 = bf16_rne(x0);
                unsigned short h1 = bf16_rne(x1);
                u0 = bf16_rne(x0 - __uint_as_float((unsigned)h0 << 16));
                u1 = bf16_rne(x1 - __uint_as_float((unsigned)h1 << 16));
            }
            p[e >> 1] = (unsigned)u0 | ((unsigned)u1 << 16);
        }
        wfrag[i] = make_uint4(p[0], p[1], p[2], p[3]);
    }
}

// ---------------------------------------------------------------------------
// Partition + h->bf16 (fused grid). Blocks < PGRID: block-chunked partition
// with register-cached edge data (dst/src/dist loaded once). Blocks >= PGRID:
// h->bf16 conversion, running CONCURRENTLY with partition.
// Record: {src | (dst_local<<17),  (log2fc_f16 << 16) | d_unorm16}
// ---------------------------------------------------------------------------
__global__ __launch_bounds__(1024) void part_conv_kernel(
    const int* __restrict__ dst,
    const int* __restrict__ src,
    const float* __restrict__ dist,
    int* __restrict__ bcursor,
    int2* __restrict__ brec,
    const float* __restrict__ h,
    unsigned short* __restrict__ hb)
{
    __shared__ int hist[NBUCK];
    __shared__ int base_[NBUCK];

    int bid = blockIdx.x;
    int tid = threadIdx.x;

    if (bid >= PGRID) {
        // ---- h -> bf16 conversion blocks
        if (hb != nullptr) {
            int idx = (bid - PGRID) * 1024 + tid;
            if (idx < N_NODES * 8) {
                const float4* p = (const float4*)(h + (size_t)idx * 8);
                float4 a = p[0], b = p[1];
                unsigned u0 = (unsigned)bf16_rne(a.x) | ((unsigned)bf16_rne(a.y) << 16);
                unsigned u1 = (unsigned)bf16_rne(a.z) | ((unsigned)bf16_rne(a.w) << 16);
                unsigned u2 = (unsigned)bf16_rne(b.x) | ((unsigned)bf16_rne(b.y) << 16);
                unsigned u3 = (unsigned)bf16_rne(b.z) | ((unsigned)bf16_rne(b.w) << 16);
                *(uint4*)(hb + (size_t)idx * 8) = make_uint4(u0, u1, u2, u3);
            }
        }
        return;
    }

    // ---- partition blocks
    for (int i = tid; i < NBUCK; i += 1024) hist[i] = 0;
    __syncthreads();

    int e0  = bid * PCHUNK;
    int rem = N_EDGES - e0;          // > 0

    int   dcache[EPT];
    int   scache[EPT];
    float vcache[EPT];
    #pragma unroll
    for (int u = 0; u < EPT; ++u) {
        int t = tid + u * 1024;
        bool v = t < rem;
        int tt = v ? (e0 + t) : e0;  // clamped, valid address
        dcache[u] = dst[tt];
        scache[u] = src[tt];
        vcache[u] = dist[tt];
        if (v) atomicAdd(&hist[dcache[u] >> BSHIFT], 1);
        else   dcache[u] = -1;
    }
    __syncthreads();

    for (int i = tid; i < NBUCK; i += 1024) {
        int hv = hist[i];
        if (hv) base_[i] = atomicAdd(&bcursor[i], hv);
        hist[i] = 0;      // reuse as local cursor
    }
    __syncthreads();

    #pragma unroll
    for (int u = 0; u < EPT; ++u) {
        int d = dcache[u];
        if (d >= 0) {
            int bkt = d >> BSHIFT;
            int r   = atomicAdd(&hist[bkt], 1);
            float dv = vcache[u];
            float fc = cutoff_fc(dv);
            float lfc = (fc > 0.0f) ? __log2f(fc) : -512.0f;
            unsigned dq = (unsigned)(fminf(fmaxf(dv, 0.0f), 1.0f) * 65535.0f + 0.5f);
            unsigned hf = (unsigned)__half_as_ushort(__float2half(lfc));
            int2 rec;
            rec.x = scache[u] | ((d & (NPB - 1)) << 17);
            rec.y = (int)((hf << 16) | dq);
            brec[(size_t)base_[bkt] + r] = rec;
        }
    }
}

// ---------------------------------------------------------------------------
// Node-sort (self-scanning): each block computes its own beg via masked
// reduction over bcursor (no separate bscan kernel). Stages bucket records
// in LDS, counts, scans, scatters -> compact per-node CSR (rec_sorted, offs).
// ---------------------------------------------------------------------------
__global__ __launch_bounds__(256) void node_sort_kernel(const int2* __restrict__ brec,
                                                        const int* __restrict__ bcursor,
                                                        int2* __restrict__ rec_sorted,
                                                        int* __restrict__ offs) {
    __shared__ int cntL[NPB];
    __shared__ int scanL[NPB];
    __shared__ int curL[NPB];
    __shared__ int red[256];
    __shared__ int2 stage[CAP];

    int b   = blockIdx.x;
    int tid = threadIdx.x;

    // beg = sum_{i<b} (bcursor[i] - i*CAP)
    int s = 0;
    for (int i = tid; i < b; i += 256) s += bcursor[i] - i * CAP;
    red[tid] = s;
    __syncthreads();
    for (int off = 128; off > 0; off >>= 1) {
        if (tid < off) red[tid] += red[tid + off];
        __syncthreads();
    }
    int beg = red[0];
    int cnt = bcursor[b] - b * CAP;
    size_t pbase = (size_t)b * CAP;
    int node0 = b << BSHIFT;

    for (int i = tid; i < NPB; i += 256) cntL[i] = 0;
    __syncthreads();

    for (int t = tid; t < cnt; t += 256) {
        int2 r = brec[pbase + t];
        stage[t] = r;
        atomicAdd(&cntL[(r.x >> 17) & (NPB - 1)], 1);
    }
    __syncthreads();

    if (tid < NPB) scanL[tid] = cntL[tid];
    __syncthreads();
    for (int off = 1; off < NPB; off <<= 1) {
        int x = 0;
        if (tid < NPB && tid >= off) x = scanL[tid - off];
        __syncthreads();
        if (tid < NPB) scanL[tid] += x;
        __syncthreads();
    }
    if (tid < NPB) {
        int excl = scanL[tid] - cntL[tid];
        curL[tid] = excl;
        int node = node0 + tid;
        if (node < N_NODES) offs[node] = beg + excl;
    }
    __syncthreads();

    for (int t = tid; t < cnt; t += 256) {
        int2 r = stage[t];
        int dl = (r.x >> 17) & (NPB - 1);
        int p  = atomicAdd(&curL[dl], 1);
        rec_sorted[(size_t)beg + p] = r;
    }
}

// ---------------------------------------------------------------------------
// Aggregation (bf16 h, proven inner loop): one wave per node, lane k owns
// feature k. Uniform record load + readfirstlane/SALU unpack,
// coef = exp2(lfc - t^2), 8x unroll, 2 acc chains.
// ---------------------------------------------------------------------------
__global__ __launch_bounds__(256) void agg_bf16_kernel(
    const unsigned short* __restrict__ hb,
    const int* __restrict__ offs,
    const int2* __restrict__ rec_sorted,
    float* __restrict__ out)
{
    int w    = threadIdx.x >> 6;
    int lane = threadIdx.x & 63;
    int node = blockIdx.x * 4 + w;
    if (node >= N_NODES) return;

    int beg = __builtin_amdgcn_readfirstlane(offs[node]);
    int end = __builtin_amdgcn_readfirstlane(offs[node + 1]);
    float muK = (float)lane * (KSCALE / 63.0f);
    float acc0 = 0.0f, acc1 = 0.0f;

#define REC(J, ACC) { \
        int2 r_ = rec_sorted[(size_t)(J)]; \
        int rx_ = __builtin_amdgcn_readfirstlane(r_.x); \
        unsigned ry_ = (unsigned)__builtin_amdgcn_readfirstlane(r_.y); \
        unsigned hvu_ = (unsigned)hb[((size_t)(rx_ & 0x1FFFF) << 6) + lane]; \
        float hv_ = __uint_as_float(hvu_ << 16); \
        float dqf_ = (float)(ry_ & 0xFFFFu); \
        float lfc_ = __half2float(__ushort_as_half((unsigned short)(ry_ >> 16))); \
        float t_  = fmaf(dqf_, (KSCALE / 65535.0f), -muK); \
        float a_  = fmaf(-t_, t_, lfc_); \
        ACC = fmaf(hv_, exp2f(a_), ACC); }

    int i = beg;
    int main_end = beg + ((end - beg) & ~7);
    for (; i < main_end; i += 8) {
        REC(i + 0, acc0) REC(i + 1, acc1) REC(i + 2, acc0) REC(i + 3, acc1)
        REC(i + 4, acc0) REC(i + 5, acc1) REC(i + 6, acc0) REC(i + 7, acc1)
    }
    for (; i < end; ++i) { REC(i, acc0) }
#undef REC

    out[(size_t)node * 64 + lane] = acc0 + acc1;
}

// ---------------------------------------------------------------------------
// Aggregation (f32 h) — used when ws too small for the bf16 copy.
// ---------------------------------------------------------------------------
__global__ __launch_bounds__(256) void agg_kernel(
    const float* __restrict__ h,
    const int* __restrict__ offs,
    const int2* __restrict__ rec_sorted,
    float* __restrict__ out)
{
    int w    = threadIdx.x >> 6;
    int lane = threadIdx.x & 63;
    int node = blockIdx.x * 4 + w;
    if (node >= N_NODES) return;

    int beg = __builtin_amdgcn_readfirstlane(offs[node]);
    int end = __builtin_amdgcn_readfirstlane(offs[node + 1]);
    float muK = (float)lane * (KSCALE / 63.0f);
    float acc0 = 0.0f, acc1 = 0.0f;

#define REC(J, ACC) { \
        int2 r_ = rec_sorted[(size_t)(J)]; \
        int rx_ = __builtin_amdgcn_readfirstlane(r_.x); \
        unsigned ry_ = (unsigned)__builtin_amdgcn_readfirstlane(r_.y); \
        float hv_ = h[((size_t)(rx_ & 0x1FFFF) << 6) + lane]; \
        float dqf_ = (float)(ry_ & 0xFFFFu); \
        float lfc_ = __half2float(__ushort_as_half((unsigned short)(ry_ >> 16))); \
        float t_  = fmaf(dqf_, (KSCALE / 65535.0f), -muK); \
        float a_  = fmaf(-t_, t_, lfc_); \
        ACC = fmaf(hv_, exp2f(a_), ACC); }

    int i = beg;
    int main_end = beg + ((end - beg) & ~7);
    for (; i < main_end; i += 8) {
        REC(i + 0, acc0) REC(i + 1, acc1) REC(i + 2, acc0) REC(i + 3, acc1)
        REC(i + 4, acc0) REC(i + 5, acc1) REC(i + 6, acc0) REC(i + 7, acc1)
    }
    for (; i < end; ++i) { REC(i, acc0) }
#undef REC

    out[(size_t)node * 64 + lane] = acc0 + acc1;
}

// ---------------------------------------------------------------------------
// MLP — MFMA. Per wave: 16 nodes. Split-bf16 3-pass.
// ---------------------------------------------------------------------------
__global__ __launch_bounds__(256) void mlp_kernel(
    float* __restrict__ io, const uint4* __restrict__ wfrag,
    const float* __restrict__ b1, const float* __restrict__ b2)
{
    __shared__ float hidL[4][16][68];

    int tid  = threadIdx.x;
    int lane = tid & 63;
    int wv   = tid >> 6;
    int grp  = blockIdx.x * 4 + wv;
    if (grp >= NGRP) return;
    int node0 = grp * 16;
    int lrow = lane & 15, lk = lane >> 4;

    const float* arow = io + (size_t)(node0 + lrow) * 64 + lk * 8;
    float4 t0 = *(const float4*)(arow);
    float4 t1 = *(const float4*)(arow + 4);
    float4 t2 = *(const float4*)(arow + 32);
    float4 t3 = *(const float4*)(arow + 36);
    short8_t Ah0, Al0, Ah1, Al1;
    split8(t0, t1, &Ah0, &Al0);
    split8(t2, t3, &Ah1, &Al1);

    f32x4_t acc[4];
    #pragma unroll
    for (int n = 0; n < 4; ++n) {
        float b = b1[n * 16 + lrow];
        acc[n] = (f32x4_t){b, b, b, b};
    }
    #pragma unroll
    for (int n = 0; n < 4; ++n) {
        short8_t wh0 = u4_to_s8(wfrag[(n) * 64 + lane]);
        short8_t wh1 = u4_to_s8(wfrag[(4 + n) * 64 + lane]);
        short8_t wl0 = u4_to_s8(wfrag[512 + n * 64 + lane]);
        short8_t wl1 = u4_to_s8(wfrag[512 + (4 + n) * 64 + lane]);
        f32x4_t c = acc[n];
        c = MFMA16(Ah0, wh0, c);
        c = MFMA16(Ah1, wh1, c);
        c = MFMA16(Ah0, wl0, c);
        c = MFMA16(Ah1, wl1, c);
        c = MFMA16(Al0, wh0, c);
        c = MFMA16(Al1, wh1, c);
        acc[n] = c;
    }

    #pragma unroll
    for (int n = 0; n < 4; ++n) {
        #pragma unroll
        for (int r = 0; r < 4; ++r) {
            float v = acc[n][r];
            float e = exp2f(v * 1.44269504089f);
            float sp = 0.69314718056f * __log2f(1.0f + e);
            v = (v > 20.0f) ? v : sp;
            hidL[wv][lk * 4 + r][n * 16 + lrow] = v;
        }
    }
    __threadfence_block();

    const float* hrow = &hidL[wv][lrow][lk * 8];
    float4 h0 = *(const float4*)(hrow);
    float4 h1 = *(const float4*)(hrow + 4);
    float4 h2 = *(const float4*)(hrow + 32);
    float4 h3 = *(const float4*)(hrow + 36);
    short8_t Bh0, Bl0, Bh1, Bl1;
    split8(h0, h1, &Bh0, &Bl0);
    split8(h2, h3, &Bh1, &Bl1);

    f32x4_t oac[4];
    #pragma unroll
    for (int n = 0; n < 4; ++n) {
        float b = b2[n * 16 + lrow];
        oac[n] = (f32x4_t){b, b, b, b};
    }
    #pragma unroll
    for (int n = 0; n < 4; ++n) {
        short8_t wh0 = u4_to_s8(wfrag[1024 + n * 64 + lane]);
        short8_t wh1 = u4_to_s8(wfrag[1024 + (4 + n) * 64 + lane]);
        short8_t wl0 = u4_to_s8(wfrag[1536 + n * 64 + lane]);
        short8_t wl1 = u4_to_s8(wfrag[1536 + (4 + n) * 64 + lane]);
        f32x4_t c = oac[n];
        c = MFMA16(Bh0, wh0, c);
        c = MFMA16(Bh1, wh1, c);
        c = MFMA16(Bh0, wl0, c);
        c = MFMA16(Bh1, wl1, c);
        c = MFMA16(Bl0, wh0, c);
        c = MFMA16(Bl1, wh1, c);
        oac[n] = c;
    }

    #pragma unroll
    for (int n = 0; n < 4; ++n) {
        #pragma unroll
        for (int r = 0; r < 4; ++r) {
            io[(size_t)(node0 + lk * 4 + r) * 64 + n * 16 + lrow] = oac[n][r];
        }
    }
}

// ---------------------------------------------------------------------------
// Fallback (ws too small): atomic scatter-add path + simple MLP.
// ---------------------------------------------------------------------------
__global__ __launch_bounds__(256) void schnet_edge_kernel(
    const float* __restrict__ h,
    const float* __restrict__ dist,
    const int* __restrict__ src_idx,
    const int* __restrict__ dst_idx,
    float* __restrict__ agg)
{
    long long idx = (long long)blockIdx.x * 256 + threadIdx.x;
    int e = (int)(idx >> 6);
    if (e >= N_EDGES) return;
    int k = (int)(idx & 63);
    float d = dist[e];
    float c = edge_coef(d, (float)k * (1.0f / 63.0f));
    int s  = src_idx[e];
    int dn = dst_idx[e];
    atomicAdd(&agg[(long long)dn * 64 + k], h[(long long)s * 64 + k] * c);
}

__global__ __launch_bounds__(256) void mlp_fallback_kernel(
    float* __restrict__ io,
    const float* __restrict__ W1, const float* __restrict__ b1,
    const float* __restrict__ W2, const float* __restrict__ b2)
{
    __shared__ float sW1[64 * 64];
    __shared__ float sW2[64 * 64];
    __shared__ float sRow[4][64];
    __shared__ float sHid[4][64];
    int tid = threadIdx.x;
    for (int i = tid; i < 4096; i += 256) { sW1[i] = W1[i]; sW2[i] = W2[i]; }
    __syncthreads();
    int lane = tid & 63, w = tid >> 6;
    float bb1 = b1[lane], bb2 = b2[lane];
    for (int base = blockIdx.x * 4; base < N_NODES; base += gridDim.x * 4) {
        int node = base + w;
        if (node < N_NODES) sRow[w][lane] = io[(size_t)node * 64 + lane];
        __syncthreads();
        float a = bb1;
        #pragma unroll
        for (int k = 0; k < 64; ++k) a = fmaf(sRow[w][k], sW1[k * 64 + lane], a);
        sHid[w][lane] = (a > 20.f) ? a : log1pf(__expf(a));
        __syncthreads();
        float c = bb2;
        #pragma unroll
        for (int k = 0; k < 64; ++k) c = fmaf(sHid[w][k], sW2[k * 64 + lane], c);
        if (node < N_NODES) io[(size_t)node * 64 + lane] = c;
        __syncthreads();
    }
}

extern "C" void kernel_launch(void* const* d_in, const int* in_sizes, int n_in,
                              void* d_out, int out_size, void* d_ws, size_t ws_size,
                              hipStream_t stream) {
    const float* h    = (const float*)d_in[0];
    const float* dist = (const float*)d_in[1];
    const float* W1   = (const float*)d_in[2];
    const float* b1   = (const float*)d_in[3];
    const float* W2   = (const float*)d_in[4];
    const float* b2   = (const float*)d_in[5];
    const int* src    = (const int*)d_in[6];
    const int* dst    = (const int*)d_in[7];
    float* out        = (float*)d_out;

    // ws layout (bytes): wfrag 32KB | [hb 12.8MB bf16 path] | rec_sorted 12.8MB |
    //                    bcursor[NBUCK] | offs[N+1]
    const size_t WFRAG_B = 32768;
    const size_t HB_B    = (size_t)N_NODES * 64 * 2;           // 12.8 MB
    const size_t RS_B    = (size_t)N_EDGES * 8;                // 12.8 MB
    const size_t INTS_B  = ((size_t)NBUCK + N_NODES + 1) * 4;
    size_t need_f32  = WFRAG_B + RS_B + INTS_B;
    size_t need_bf16 = WFRAG_B + HB_B + RS_B + INTS_B;

    if (ws_size >= need_f32) {
        bool use_bf16 = (ws_size >= need_bf16);
        char* p = (char*)d_ws;
        uint4* wfrag = (uint4*)p;              p += WFRAG_B;
        unsigned short* hb = (unsigned short*)p;
        if (use_bf16)                          p += HB_B;
        int2* rec_sorted = (int2*)p;           p += RS_B;
        int* bcursor = (int*)p;                // NBUCK
        int* offs    = bcursor + NBUCK;        // N+1

        // padded bucket staging in d_out (782*4088 recs = 25.57MB <= 25.6MB)
        int2* brec = (int2*)d_out;

        init_kernel<<<16, 256, 0, stream>>>(bcursor, offs, W1, W2, wfrag);
        int pcgrid = use_bf16 ? (PGRID + HBLK) : PGRID;
        part_conv_kernel<<<pcgrid, 1024, 0, stream>>>(dst, src, dist, bcursor, brec,
                                                      h, use_bf16 ? hb : nullptr);
        node_sort_kernel<<<NBUCK, 256, 0, stream>>>(brec, bcursor, rec_sorted, offs);
        if (use_bf16)
            agg_bf16_kernel<<<N_NODES / 4, 256, 0, stream>>>(hb, offs, rec_sorted, out);
        else
            agg_kernel<<<N_NODES / 4, 256, 0, stream>>>(h, offs, rec_sorted, out);
        mlp_kernel<<<(NGRP + 3) / 4, 256, 0, stream>>>(out, wfrag, b1, b2);
    } else {
        hipMemsetAsync(out, 0, (size_t)N_NODES * IN_FEATS * sizeof(float), stream);
        long long total = (long long)N_EDGES * 64;
        schnet_edge_kernel<<<(int)((total + 255) / 256), 256, 0, stream>>>(
            h, dist, src, dst, out);
        mlp_fallback_kernel<<<2048, 256, 0, stream>>>(out, W1, b1, W2, b2);
    }
}